// Round 12
// baseline (573.078 us; speedup 1.0000x reference)
//
#include <hip/hip_runtime.h>

typedef __attribute__((ext_vector_type(8))) short short8v;
typedef __attribute__((ext_vector_type(4))) float float4v;

__device__ __forceinline__ ushort f2bf(float f) {
  union { float f; unsigned u; } v; v.f = f;
  unsigned r = v.u + 0x7fffu + ((v.u >> 16) & 1u);  // RNE
  return (ushort)(r >> 16);
}
__device__ __forceinline__ float bf2f(ushort h) {
  union { unsigned u; float f; } v; v.u = ((unsigned)h) << 16;
  return v.f;
}
__device__ __forceinline__ float ubf(unsigned u, int hi) {
  return __uint_as_float(hi ? (u & 0xFFFF0000u) : (u << 16));
}

// ---------------- CSR build (incoming edges per dst, self-loop appended) ----------------
// Partitioned by dst range into 8 block-groups (~XCDs): scatter targets stay in
// one XCD's L2 (fixes r10's 16x write amplification: 106MB for 6.4MB payload).
__global__ void count_part(const int* __restrict__ dstp, int* __restrict__ cnt,
                           int E, int N, int nblk) {
  int grp = blockIdx.x & 7;
  int gb = blockIdx.x >> 3;
  int gn = nblk >> 3;
  int lo = (int)(((long long)N * grp) >> 3);
  int hi = (int)(((long long)N * (grp + 1)) >> 3);
  for (int e = gb * blockDim.x + threadIdx.x; e < E; e += gn * blockDim.x) {
    int d = dstp[e];
    if (d >= lo && d < hi) atomicAdd(&cnt[d], 1);
  }
}

__global__ void fill_part(const int* __restrict__ srcp, const int* __restrict__ dstp,
                          const int* __restrict__ rowptr, int* __restrict__ cur,
                          int* __restrict__ csr_src, int E, int N, int nblk) {
  int grp = blockIdx.x & 7;
  int gb = blockIdx.x >> 3;
  int gn = nblk >> 3;
  int lo = (int)(((long long)N * grp) >> 3);
  int hi = (int)(((long long)N * (grp + 1)) >> 3);
  for (int e = gb * blockDim.x + threadIdx.x; e < E; e += gn * blockDim.x) {
    int d = dstp[e];
    if (d >= lo && d < hi) {
      int pos = atomicAdd(&cur[d], 1);
      csr_src[rowptr[d] + pos] = srcp[e];
    }
  }
}

// per-1024-block inclusive scan over (cnt[i]+1); raw block sums to bsum
__global__ __launch_bounds__(1024)
void scan_blocks(const int* __restrict__ cnt, int* __restrict__ tscan,
                 int* __restrict__ bsum, int n) {
  __shared__ int sh[1024];
  int t = threadIdx.x;
  int i = blockIdx.x * 1024 + t;
  sh[t] = (i < n) ? cnt[i] + 1 : 0;
  __syncthreads();
  for (int off = 1; off < 1024; off <<= 1) {
    int u = (t >= off) ? sh[t - off] : 0;
    __syncthreads();
    sh[t] += u;
    __syncthreads();
  }
  if (i < n) tscan[i] = sh[t];
  if (t == 1023) bsum[blockIdx.x] = sh[1023];
}

// fused: scan of bsum + rowptr + self-loop slot + cur-zeroing + total
__global__ __launch_bounds__(1024)
void scan_final(int* __restrict__ cnt, const int* __restrict__ tscan,
                const int* __restrict__ bsum, int* __restrict__ rowptr,
                int* __restrict__ csr_src, int n, int nb) {
  __shared__ int sh[1024];
  int t = threadIdx.x;
  sh[t] = (t < nb) ? bsum[t] : 0;
  __syncthreads();
  for (int off = 1; off < 1024; off <<= 1) {
    int u = (t >= off) ? sh[t - off] : 0;
    __syncthreads();
    sh[t] += u;
    __syncthreads();
  }
  int i = blockIdx.x * 1024 + t;
  if (i < n) {
    int bpref = (blockIdx.x == 0) ? 0 : sh[blockIdx.x - 1];
    int incl = bpref + tscan[i];
    rowptr[i] = incl - (cnt[i] + 1);
    csr_src[incl - 1] = i;                // self-loop in node's LAST slot
    cnt[i] = 0;                           // becomes `cur` for fill_part
  }
  if (blockIdx.x == nb - 1 && t == 0) rowptr[n] = sh[nb - 1];
}

// Pack all 8 weight matrices in ONE launch.
struct PackArgs {
  const float* w[8];
  ushort* o[8];
  int nout[8];
};
__global__ __launch_bounds__(256)
void pack_all(PackArgs pa) {
  int wsel = blockIdx.x >> 3;
  int sub = blockIdx.x & 7;
  const float* W = pa.w[wsel];
  ushort* pk = pa.o[wsel];
  int NOUT = pa.nout[wsel];
  int NT = NOUT / 16;
  int total = NT * 4 * 64;
  int t = sub * 256 + threadIdx.x;
  if (t >= total) return;
  int lane = t & 63;
  int ks = (t >> 6) & 3;
  int nt = t >> 8;
  int col = nt * 16 + (lane & 15);
  int k0 = ks * 32 + (lane >> 4) * 8;
  ushort h[8], l[8];
#pragma unroll
  for (int j = 0; j < 8; ++j) {
    float v = W[(size_t)(k0 + j) * NOUT + col];
    h[j] = f2bf(v);
    l[j] = f2bf(v - bf2f(h[j]));
  }
  size_t fb = ((size_t)(nt * 4 + ks) * 64 + lane) * 8;
  size_t fragsz = (size_t)total * 8;
#pragma unroll
  for (int j = 0; j < 8; ++j) { pk[fb + j] = h[j]; pk[fragsz + fb + j] = l[j]; }
}

// ---------- Fused triple MFMA GEMM: C0,C1 bf16; C2 fp32 ----------
// AF32: A is raw fp32 (layer 1, x) -> split hi/lo in-kernel (kills split kernel).
template<bool AF32>
__global__ __launch_bounds__(512)
void gemm3_mfma(const void* __restrict__ A1, const void* __restrict__ A2,
                const ushort* __restrict__ W0, const ushort* __restrict__ W1,
                const ushort* __restrict__ W2,
                const float* __restrict__ b0, const float* __restrict__ b1,
                const float* __restrict__ b2,
                ushort* __restrict__ C0b, ushort* __restrict__ C1b,
                float* __restrict__ C2, int M) {
  int tid = threadIdx.x;
  int w = tid >> 6, lane = tid & 63;
  int l15 = lane & 15, lh = lane >> 4;
  int row0 = blockIdx.x * 64;

  const ushort* Wp[3] = {W0, W1, W2};

  int arow[4];
#pragma unroll
  for (int mt = 0; mt < 4; ++mt) { int rr = row0 + mt * 16 + l15; arow[mt] = rr < M ? rr : M - 1; }

  float4v acc[3][4];
#pragma unroll
  for (int p = 0; p < 3; ++p)
#pragma unroll
    for (int mt = 0; mt < 4; ++mt) {
      acc[p][mt][0] = 0.f; acc[p][mt][1] = 0.f; acc[p][mt][2] = 0.f; acc[p][mt][3] = 0.f;
    }

  const size_t fragsz = (size_t)8 * 4 * 64 * 8;  // NT=8
#pragma unroll 1
  for (int ks = 0; ks < 4; ++ks) {
    short8v bh[3], bl[3];
    size_t fb = ((size_t)(w * 4 + ks) * 64 + lane) * 8;
#pragma unroll
    for (int p = 0; p < 3; ++p) {
      bh[p] = *(const short8v*)(Wp[p] + fb);
      bl[p] = *(const short8v*)(Wp[p] + fragsz + fb);
    }
#pragma unroll
    for (int mt = 0; mt < 4; ++mt) {
      size_t ao = (size_t)arow[mt] * 128 + ks * 32 + lh * 8;
      short8v ah, al;
      if constexpr (AF32) {
        const float* Af = (const float*)A1;
        float4 f0 = *(const float4*)(Af + ao);
        float4 f1 = *(const float4*)(Af + ao + 4);
        float fv[8] = {f0.x, f0.y, f0.z, f0.w, f1.x, f1.y, f1.z, f1.w};
#pragma unroll
        for (int j = 0; j < 8; ++j) {
          ushort h = f2bf(fv[j]);
          ah[j] = (short)h;
          al[j] = (short)f2bf(fv[j] - bf2f(h));
        }
      } else {
        ah = *(const short8v*)((const ushort*)A1 + ao);
        al = *(const short8v*)((const ushort*)A2 + ao);
      }
#pragma unroll
      for (int p = 0; p < 3; ++p) {
        acc[p][mt] = __builtin_amdgcn_mfma_f32_16x16x32_bf16(ah, bh[p], acc[p][mt], 0, 0, 0);
        acc[p][mt] = __builtin_amdgcn_mfma_f32_16x16x32_bf16(ah, bl[p], acc[p][mt], 0, 0, 0);
        acc[p][mt] = __builtin_amdgcn_mfma_f32_16x16x32_bf16(al, bh[p], acc[p][mt], 0, 0, 0);
      }
    }
  }

  int col = w * 16 + l15;
  float bb0 = b0[col], bb1 = b1[col], bb2 = b2[col];
#pragma unroll
  for (int mt = 0; mt < 4; ++mt) {
#pragma unroll
    for (int r = 0; r < 4; ++r) {
      int rr = row0 + mt * 16 + lh * 4 + r;
      if (rr < M) {
        C0b[(size_t)rr * 128 + col] = f2bf(acc[0][mt][r] + bb0);
        C1b[(size_t)rr * 128 + col] = f2bf(acc[1][mt][r] + bb1);
        C2[(size_t)rr * 128 + col] = acc[2][mt][r] + bb2;
      }
    }
  }
}

// ---------- per-node att dots: dl[i][h] = dot(att_h, xl_i), dr likewise ----------
// One wave per node; lane holds 2 elems. Reduce within RL-lane head groups.
template<int H>
__global__ __launch_bounds__(256)
void dot_att(const ushort* __restrict__ xlb, const ushort* __restrict__ xrb,
             const float* __restrict__ att, float* __restrict__ dl,
             float* __restrict__ dr, int n) {
  constexpr int RL = (H == 4) ? 16 : 64;  // lanes per head (32 elems or 128)
  int wid = blockIdx.x * 4 + (threadIdx.x >> 6);
  if (wid >= n) return;
  int lane = threadIdx.x & 63;
  size_t base = (size_t)wid * 128 + lane * 2;
  float a0 = att[lane * 2], a1 = att[lane * 2 + 1];
  unsigned ul = *(const unsigned*)(xlb + base);
  unsigned ur = *(const unsigned*)(xrb + base);
  float pl = fmaf(a1, ubf(ul, 1), a0 * ubf(ul, 0));
  float pr = fmaf(a1, ubf(ur, 1), a0 * ubf(ur, 0));
#pragma unroll
  for (int o = 1; o < RL; o <<= 1) {
    pl += __shfl_xor(pl, o, 64);
    pr += __shfl_xor(pr, o, 64);
  }
  if ((lane & (RL - 1)) == 0) {
    int h = lane / RL;
    dl[(size_t)wid * H + h] = pl;
    dr[(size_t)wid * H + h] = pr;
  }
}

// ---------- Fused MLP head: out = relu(A@W1+b1) @ W2 + b2 ----------
__global__ __launch_bounds__(256)
void mlp_fused(const ushort* __restrict__ Ahi, const ushort* __restrict__ Alo,
               const ushort* __restrict__ W1pk, const float* __restrict__ b1,
               const ushort* __restrict__ W2pk, const float* __restrict__ b2,
               float* __restrict__ out, int M) {
  __shared__ ushort m1[2][16][64][8];   // [hi/lo][k>>3][row][k&7]
  int tid = threadIdx.x;
  int w = tid >> 6, lane = tid & 63;
  int l15 = lane & 15, lh = lane >> 4;
  int row0 = blockIdx.x * 64;

  int arow[4];
#pragma unroll
  for (int mt = 0; mt < 4; ++mt) { int rr = row0 + mt * 16 + l15; arow[mt] = rr < M ? rr : M - 1; }

  float4v acc1[4][2];
#pragma unroll
  for (int mt = 0; mt < 4; ++mt)
#pragma unroll
    for (int j = 0; j < 2; ++j) {
      acc1[mt][j][0] = 0.f; acc1[mt][j][1] = 0.f; acc1[mt][j][2] = 0.f; acc1[mt][j][3] = 0.f;
    }
  const size_t fragsz1 = (size_t)8 * 4 * 64 * 8;
#pragma unroll 1
  for (int ks = 0; ks < 4; ++ks) {
    short8v bh[2], bl[2];
#pragma unroll
    for (int nt2 = 0; nt2 < 2; ++nt2) {
      size_t fb = ((size_t)((w * 2 + nt2) * 4 + ks) * 64 + lane) * 8;
      bh[nt2] = *(const short8v*)(W1pk + fb);
      bl[nt2] = *(const short8v*)(W1pk + fragsz1 + fb);
    }
#pragma unroll
    for (int mt = 0; mt < 4; ++mt) {
      size_t ao = (size_t)arow[mt] * 128 + ks * 32 + lh * 8;
      short8v ah = *(const short8v*)(Ahi + ao);
      short8v al = *(const short8v*)(Alo + ao);
#pragma unroll
      for (int nt2 = 0; nt2 < 2; ++nt2) {
        acc1[mt][nt2] = __builtin_amdgcn_mfma_f32_16x16x32_bf16(ah, bh[nt2], acc1[mt][nt2], 0, 0, 0);
        acc1[mt][nt2] = __builtin_amdgcn_mfma_f32_16x16x32_bf16(ah, bl[nt2], acc1[mt][nt2], 0, 0, 0);
        acc1[mt][nt2] = __builtin_amdgcn_mfma_f32_16x16x32_bf16(al, bh[nt2], acc1[mt][nt2], 0, 0, 0);
      }
    }
  }
#pragma unroll
  for (int nt2 = 0; nt2 < 2; ++nt2) {
    int col = (w * 2 + nt2) * 16 + l15;
    float bb = b1[col];
    int kf = col >> 3, kr = col & 7;
#pragma unroll
    for (int mt = 0; mt < 4; ++mt) {
#pragma unroll
      for (int r = 0; r < 4; ++r) {
        int row = mt * 16 + lh * 4 + r;
        float v = fmaxf(acc1[mt][nt2][r] + bb, 0.f);
        ushort h = f2bf(v);
        m1[0][kf][row][kr] = h;
        m1[1][kf][row][kr] = f2bf(v - bf2f(h));
      }
    }
  }
  __syncthreads();

  float4v acc2[4];
#pragma unroll
  for (int mt = 0; mt < 4; ++mt) {
    acc2[mt][0] = 0.f; acc2[mt][1] = 0.f; acc2[mt][2] = 0.f; acc2[mt][3] = 0.f;
  }
  const size_t fragsz2 = (size_t)4 * 4 * 64 * 8;
#pragma unroll 1
  for (int ks = 0; ks < 4; ++ks) {
    size_t fb = ((size_t)(w * 4 + ks) * 64 + lane) * 8;
    short8v bh = *(const short8v*)(W2pk + fb);
    short8v bl = *(const short8v*)(W2pk + fragsz2 + fb);
#pragma unroll
    for (int mt = 0; mt < 4; ++mt) {
      int row = mt * 16 + l15;
      short8v ah = *(const short8v*)&m1[0][ks * 4 + lh][row][0];
      short8v al = *(const short8v*)&m1[1][ks * 4 + lh][row][0];
      acc2[mt] = __builtin_amdgcn_mfma_f32_16x16x32_bf16(ah, bh, acc2[mt], 0, 0, 0);
      acc2[mt] = __builtin_amdgcn_mfma_f32_16x16x32_bf16(ah, bl, acc2[mt], 0, 0, 0);
      acc2[mt] = __builtin_amdgcn_mfma_f32_16x16x32_bf16(al, bh, acc2[mt], 0, 0, 0);
    }
  }
  int col = w * 16 + l15;
  float bb = b2[col];
#pragma unroll
  for (int mt = 0; mt < 4; ++mt) {
#pragma unroll
    for (int r = 0; r < 4; ++r) {
      int rr = row0 + mt * 16 + lh * 4 + r;
      if (rr < M) out[(size_t)rr * 64 + col] = acc2[mt][r] + bb;
    }
  }
}

// ---------- GATv2 aggregation: one wave per node, 2 edges per wave ----------
// Factored logit: logit = 0.6*(dl[s]+dr[d]) + 0.4*sum(att*|xl+xr|).
// Per-elem edge work: add + fma(|.|) (2 VALU vs 4). dl gather is L2-resident.
template<int H, bool SPLIT>
__global__ __launch_bounds__(256)
void gat_agg(const ushort* __restrict__ xlb, const ushort* __restrict__ xrb,
             const float* __restrict__ skip, const float* __restrict__ att,
             const float* __restrict__ dl, const float* __restrict__ dr,
             const float* __restrict__ gbias, const int* __restrict__ rowptr,
             const int* __restrict__ csr_src, float* __restrict__ out,
             ushort* __restrict__ outhi, ushort* __restrict__ outlo,
             int n, int relu) {
  constexpr int GL = (128 / H) / 4;      // lanes per head group: H=4 -> 8, H=1 -> 32
  constexpr int HS = (H == 4) ? 3 : 5;   // head = sub >> HS
  int wid = blockIdx.x * (blockDim.x >> 6) + (threadIdx.x >> 6);
  if (wid >= n) return;
  int lane = threadIdx.x & 63;
  int half = lane >> 5;
  int sub = lane & 31;
  int head = sub >> HS;
  size_t base = (size_t)wid * 128 + sub * 4;
  uint2 ur = *(const uint2*)(xrb + base);
  float4 xrv;
  xrv.x = ubf(ur.x, 0); xrv.y = ubf(ur.x, 1);
  xrv.z = ubf(ur.y, 0); xrv.w = ubf(ur.y, 1);
  float4 av = *(const float4*)(att + sub * 4);
  float drd = dr[(size_t)wid * H + head];
  float ax = 0.f, ay = 0.f, az = 0.f, aw = 0.f;
  float denom = 0.f;
  int e0 = rowptr[wid], e1 = rowptr[wid + 1];

  int idx = e0 + half;
  for (; idx + 2 < e1; idx += 4) {
    int s0 = csr_src[idx], s1 = csr_src[idx + 2];
    float dls0 = dl[(size_t)s0 * H + head];
    float dls1 = dl[(size_t)s1 * H + head];
    uint2 u0 = *(const uint2*)(xlb + (size_t)s0 * 128 + sub * 4);
    uint2 u1 = *(const uint2*)(xlb + (size_t)s1 * 128 + sub * 4);
    float4 v0, v1;
    v0.x = ubf(u0.x, 0); v0.y = ubf(u0.x, 1); v0.z = ubf(u0.y, 0); v0.w = ubf(u0.y, 1);
    v1.x = ubf(u1.x, 0); v1.y = ubf(u1.x, 1); v1.z = ubf(u1.y, 0); v1.w = ubf(u1.y, 1);
    float p0, p1;
    p0 = av.x * fabsf(v0.x + xrv.x);
    p0 = fmaf(av.y, fabsf(v0.y + xrv.y), p0);
    p0 = fmaf(av.z, fabsf(v0.z + xrv.z), p0);
    p0 = fmaf(av.w, fabsf(v0.w + xrv.w), p0);
    p1 = av.x * fabsf(v1.x + xrv.x);
    p1 = fmaf(av.y, fabsf(v1.y + xrv.y), p1);
    p1 = fmaf(av.z, fabsf(v1.z + xrv.z), p1);
    p1 = fmaf(av.w, fabsf(v1.w + xrv.w), p1);
#pragma unroll
    for (int o = 1; o < GL; o <<= 1) {
      p0 += __shfl_xor(p0, o, 64);
      p1 += __shfl_xor(p1, o, 64);
    }
    float w0 = __expf(fmaf(0.4f, p0, 0.6f * (dls0 + drd)));
    float w1 = __expf(fmaf(0.4f, p1, 0.6f * (dls1 + drd)));
    denom += w0 + w1;
    ax += w0 * v0.x + w1 * v1.x;
    ay += w0 * v0.y + w1 * v1.y;
    az += w0 * v0.z + w1 * v1.z;
    aw += w0 * v0.w + w1 * v1.w;
  }
  for (; idx < e1; idx += 2) {
    int s0 = csr_src[idx];
    float dls0 = dl[(size_t)s0 * H + head];
    uint2 u0 = *(const uint2*)(xlb + (size_t)s0 * 128 + sub * 4);
    float4 v0;
    v0.x = ubf(u0.x, 0); v0.y = ubf(u0.x, 1); v0.z = ubf(u0.y, 0); v0.w = ubf(u0.y, 1);
    float p0;
    p0 = av.x * fabsf(v0.x + xrv.x);
    p0 = fmaf(av.y, fabsf(v0.y + xrv.y), p0);
    p0 = fmaf(av.z, fabsf(v0.z + xrv.z), p0);
    p0 = fmaf(av.w, fabsf(v0.w + xrv.w), p0);
#pragma unroll
    for (int o = 1; o < GL; o <<= 1) p0 += __shfl_xor(p0, o, 64);
    float w0 = __expf(fmaf(0.4f, p0, 0.6f * (dls0 + drd)));
    denom += w0;
    ax += w0 * v0.x;
    ay += w0 * v0.y;
    az += w0 * v0.z;
    aw += w0 * v0.w;
  }

  // combine the two halves
  ax += __shfl_xor(ax, 32, 64);
  ay += __shfl_xor(ay, 32, 64);
  az += __shfl_xor(az, 32, 64);
  aw += __shfl_xor(aw, 32, 64);
  denom += __shfl_xor(denom, 32, 64);

  if (half == 0) {
    float inv = 1.f / denom;
    float4 sk = *(const float4*)(skip + base);
    float4 gb = *(const float4*)(gbias + sub * 4);
    float o0 = ax * inv + gb.x + sk.x;
    float o1 = ay * inv + gb.y + sk.y;
    float o2 = az * inv + gb.z + sk.z;
    float o3 = aw * inv + gb.w + sk.w;
    if (relu) {
      o0 = fmaxf(o0, 0.f); o1 = fmaxf(o1, 0.f);
      o2 = fmaxf(o2, 0.f); o3 = fmaxf(o3, 0.f);
    }
    if (SPLIT) {
      ushort h0 = f2bf(o0), h1 = f2bf(o1), h2 = f2bf(o2), h3 = f2bf(o3);
      *(ushort4*)(outhi + base) = make_ushort4(h0, h1, h2, h3);
      *(ushort4*)(outlo + base) = make_ushort4(f2bf(o0 - bf2f(h0)), f2bf(o1 - bf2f(h1)),
                                               f2bf(o2 - bf2f(h2)), f2bf(o3 - bf2f(h3)));
    } else {
      *(float4*)(out + base) = make_float4(o0, o1, o2, o3);
    }
  }
}

extern "C" void kernel_launch(void* const* d_in, const int* in_sizes, int n_in,
                              void* d_out, int out_size, void* d_ws, size_t ws_size,
                              hipStream_t stream) {
  const float* x       = (const float*)d_in[0];
  const int* ei        = (const int*)d_in[1];
  const float* Wl1     = (const float*)d_in[2];
  const float* bl1     = (const float*)d_in[3];
  const float* Wr1     = (const float*)d_in[4];
  const float* br1     = (const float*)d_in[5];
  const float* att1    = (const float*)d_in[6];
  const float* b1      = (const float*)d_in[7];
  const float* Wl2     = (const float*)d_in[8];
  const float* bl2     = (const float*)d_in[9];
  const float* Wr2     = (const float*)d_in[10];
  const float* br2     = (const float*)d_in[11];
  const float* att2    = (const float*)d_in[12];
  const float* b2      = (const float*)d_in[13];
  const float* skip1_w = (const float*)d_in[14];
  const float* skip1_b = (const float*)d_in[15];
  const float* skip2_w = (const float*)d_in[16];
  const float* skip2_b = (const float*)d_in[17];
  const float* mlp1_w  = (const float*)d_in[18];
  const float* mlp1_b  = (const float*)d_in[19];
  const float* mlp2_w  = (const float*)d_in[20];
  const float* mlp2_b  = (const float*)d_in[21];

  const int N = in_sizes[0] / 128;
  const int E = in_sizes[1] / 2;
  float* out = (float*)d_out;

  char* ws = (char*)d_ws;
  size_t off = 0;
  auto alloc = [&](size_t bytes) -> void* {
    void* p = ws + off;
    off = (off + bytes + 255) & ~(size_t)255;
    return p;
  };
  int* rowptr  = (int*)alloc((size_t)(N + 1) * sizeof(int));
  int* cnt     = (int*)alloc((size_t)N * sizeof(int));
  int* tscan   = (int*)alloc((size_t)N * sizeof(int));
  int* bsum    = (int*)alloc((size_t)1024 * sizeof(int));
  int* csr_src = (int*)alloc((size_t)(E + N) * sizeof(int));
  ushort* wpk[8];
  for (int i = 0; i < 8; ++i) wpk[i] = (ushort*)alloc(128 * 128 * 2 * sizeof(ushort));
  ushort* p0hi = (ushort*)alloc((size_t)N * 128 * sizeof(ushort));
  ushort* p0lo = (ushort*)alloc((size_t)N * 128 * sizeof(ushort));
  ushort* xlb  = (ushort*)alloc((size_t)N * 128 * sizeof(ushort));
  ushort* xrb  = (ushort*)alloc((size_t)N * 128 * sizeof(ushort));
  float* bufC  = (float*)alloc((size_t)N * 128 * sizeof(float));
  float* dl    = (float*)alloc((size_t)N * 4 * sizeof(float));
  float* dr    = (float*)alloc((size_t)N * 4 * sizeof(float));

  const int* srcp = ei;
  const int* dstp = ei + E;

  const int ggrid = (N + 63) / 64;
  const int agrid = (N + 3) / 4;
  const int nb = (N + 1023) / 1024;
  const int PARTB = 2048;

  // CSR by dst with embedded self-loops (partitioned count/fill)
  hipMemsetAsync(cnt, 0, (size_t)N * sizeof(int), stream);
  count_part<<<PARTB, 256, 0, stream>>>(dstp, cnt, E, N, PARTB);
  scan_blocks<<<nb, 1024, 0, stream>>>(cnt, tscan, bsum, N);
  scan_final<<<nb, 1024, 0, stream>>>(cnt, tscan, bsum, rowptr, csr_src, N, nb);
  fill_part<<<PARTB, 256, 0, stream>>>(srcp, dstp, rowptr, cnt, csr_src, E, N, PARTB);

  // Weight packs (one launch)
  PackArgs pa;
  pa.w[0] = Wl1;    pa.o[0] = wpk[0]; pa.nout[0] = 128;
  pa.w[1] = Wr1;    pa.o[1] = wpk[1]; pa.nout[1] = 128;
  pa.w[2] = skip1_w;pa.o[2] = wpk[2]; pa.nout[2] = 128;
  pa.w[3] = Wl2;    pa.o[3] = wpk[3]; pa.nout[3] = 128;
  pa.w[4] = Wr2;    pa.o[4] = wpk[4]; pa.nout[4] = 128;
  pa.w[5] = skip2_w;pa.o[5] = wpk[5]; pa.nout[5] = 128;
  pa.w[6] = mlp1_w; pa.o[6] = wpk[6]; pa.nout[6] = 128;
  pa.w[7] = mlp2_w; pa.o[7] = wpk[7]; pa.nout[7] = 64;
  pack_all<<<64, 256, 0, stream>>>(pa);

  // ---- Layer 1: fused {xl1, xr1, skip1} GEMM (fp32 A, split in-kernel) ----
  gemm3_mfma<true><<<ggrid, 512, 0, stream>>>((const void*)x, nullptr,
                                              wpk[0], wpk[1], wpk[2],
                                              bl1, br1, skip1_b, xlb, xrb, bufC, N);
  dot_att<4><<<agrid, 256, 0, stream>>>(xlb, xrb, att1, dl, dr, N);
  gat_agg<4, true><<<agrid, 256, 0, stream>>>(xlb, xrb, bufC, att1, dl, dr, b1,
                                              rowptr, csr_src, nullptr, p0hi, p0lo, N, 1);

  // ---- Layer 2: fused {xl2, xr2, skip2} GEMM ----
  gemm3_mfma<false><<<ggrid, 512, 0, stream>>>((const void*)p0hi, (const void*)p0lo,
                                               wpk[3], wpk[4], wpk[5],
                                               bl2, br2, skip2_b, xlb, xrb, bufC, N);
  dot_att<1><<<agrid, 256, 0, stream>>>(xlb, xrb, att2, dl, dr, N);
  gat_agg<1, true><<<agrid, 256, 0, stream>>>(xlb, xrb, bufC, att2, dl, dr, b2,
                                              rowptr, csr_src, nullptr, p0hi, p0lo, N, 0);

  // ---- Fused MLP head ----
  mlp_fused<<<ggrid, 256, 0, stream>>>(p0hi, p0lo, wpk[6], mlp1_b, wpk[7], mlp2_b, out, N);
}

// Round 13
// 549.883 us; speedup vs baseline: 1.0422x; 1.0422x over previous
//
#include <hip/hip_runtime.h>

#define LEAK 0.2f

typedef __attribute__((ext_vector_type(8))) short short8v;
typedef __attribute__((ext_vector_type(4))) float float4v;

__device__ __forceinline__ ushort f2bf(float f) {
  union { float f; unsigned u; } v; v.f = f;
  unsigned r = v.u + 0x7fffu + ((v.u >> 16) & 1u);  // RNE
  return (ushort)(r >> 16);
}
__device__ __forceinline__ float bf2f(ushort h) {
  union { unsigned u; float f; } v; v.u = ((unsigned)h) << 16;
  return v.f;
}
__device__ __forceinline__ float ubf(unsigned u, int hi) {
  return __uint_as_float(hi ? (u & 0xFFFF0000u) : (u << 16));
}
// leaky_relu(t, 0.2) = 0.6t + 0.4|t|
__device__ __forceinline__ float lrelu(float t) {
  return fmaf(0.4f, fabsf(t), 0.6f * t);
}

// ---------------- CSR build (incoming edges per dst, self-loop appended) ----------------
// Partitioned by dst range into 8 block-groups (~XCDs): scatter targets stay in
// one XCD's L2 (fixes r10's 16x write amplification).
__global__ void count_part(const int* __restrict__ dstp, int* __restrict__ cnt,
                           int E, int N, int nblk) {
  int grp = blockIdx.x & 7;
  int gb = blockIdx.x >> 3;
  int gn = nblk >> 3;
  int lo = (int)(((long long)N * grp) >> 3);
  int hi = (int)(((long long)N * (grp + 1)) >> 3);
  for (int e = gb * blockDim.x + threadIdx.x; e < E; e += gn * blockDim.x) {
    int d = dstp[e];
    if (d >= lo && d < hi) atomicAdd(&cnt[d], 1);
  }
}

__global__ void fill_part(const int* __restrict__ srcp, const int* __restrict__ dstp,
                          const int* __restrict__ rowptr, int* __restrict__ cur,
                          int* __restrict__ csr_src, int E, int N, int nblk) {
  int grp = blockIdx.x & 7;
  int gb = blockIdx.x >> 3;
  int gn = nblk >> 3;
  int lo = (int)(((long long)N * grp) >> 3);
  int hi = (int)(((long long)N * (grp + 1)) >> 3);
  for (int e = gb * blockDim.x + threadIdx.x; e < E; e += gn * blockDim.x) {
    int d = dstp[e];
    if (d >= lo && d < hi) {
      int pos = atomicAdd(&cur[d], 1);
      csr_src[rowptr[d] + pos] = srcp[e];
    }
  }
}

// per-1024-block inclusive scan over (cnt[i]+1); raw block sums to bsum
__global__ __launch_bounds__(1024)
void scan_blocks(const int* __restrict__ cnt, int* __restrict__ tscan,
                 int* __restrict__ bsum, int n) {
  __shared__ int sh[1024];
  int t = threadIdx.x;
  int i = blockIdx.x * 1024 + t;
  sh[t] = (i < n) ? cnt[i] + 1 : 0;
  __syncthreads();
  for (int off = 1; off < 1024; off <<= 1) {
    int u = (t >= off) ? sh[t - off] : 0;
    __syncthreads();
    sh[t] += u;
    __syncthreads();
  }
  if (i < n) tscan[i] = sh[t];
  if (t == 1023) bsum[blockIdx.x] = sh[1023];
}

// fused: scan of bsum + rowptr + self-loop slot + cur-zeroing + total
__global__ __launch_bounds__(1024)
void scan_final(int* __restrict__ cnt, const int* __restrict__ tscan,
                const int* __restrict__ bsum, int* __restrict__ rowptr,
                int* __restrict__ csr_src, int n, int nb) {
  __shared__ int sh[1024];
  int t = threadIdx.x;
  sh[t] = (t < nb) ? bsum[t] : 0;
  __syncthreads();
  for (int off = 1; off < 1024; off <<= 1) {
    int u = (t >= off) ? sh[t - off] : 0;
    __syncthreads();
    sh[t] += u;
    __syncthreads();
  }
  int i = blockIdx.x * 1024 + t;
  if (i < n) {
    int bpref = (blockIdx.x == 0) ? 0 : sh[blockIdx.x - 1];
    int incl = bpref + tscan[i];
    rowptr[i] = incl - (cnt[i] + 1);
    csr_src[incl - 1] = i;                // self-loop in node's LAST slot
    cnt[i] = 0;                           // becomes `cur` for fill_part
  }
  if (blockIdx.x == nb - 1 && t == 0) rowptr[n] = sh[nb - 1];
}

// ---------------- bf16 split ----------------
__global__ void split_f32(const float* __restrict__ a, ushort* __restrict__ hi,
                          ushort* __restrict__ lo, int n) {
  int i = (blockIdx.x * blockDim.x + threadIdx.x) * 4;
  if (i >= n) return;
  float4 v = *(const float4*)(a + i);
  ushort h[4], l[4];
  float vv[4] = {v.x, v.y, v.z, v.w};
#pragma unroll
  for (int j = 0; j < 4; ++j) {
    h[j] = f2bf(vv[j]);
    l[j] = f2bf(vv[j] - bf2f(h[j]));
  }
  *(ushort4*)(hi + i) = make_ushort4(h[0], h[1], h[2], h[3]);
  *(ushort4*)(lo + i) = make_ushort4(l[0], l[1], l[2], l[3]);
}

// Pack all 8 weight matrices in ONE launch.
struct PackArgs {
  const float* w[8];
  ushort* o[8];
  int nout[8];
};
__global__ __launch_bounds__(256)
void pack_all(PackArgs pa) {
  int wsel = blockIdx.x >> 3;
  int sub = blockIdx.x & 7;
  const float* W = pa.w[wsel];
  ushort* pk = pa.o[wsel];
  int NOUT = pa.nout[wsel];
  int NT = NOUT / 16;
  int total = NT * 4 * 64;
  int t = sub * 256 + threadIdx.x;
  if (t >= total) return;
  int lane = t & 63;
  int ks = (t >> 6) & 3;
  int nt = t >> 8;
  int col = nt * 16 + (lane & 15);
  int k0 = ks * 32 + (lane >> 4) * 8;
  ushort h[8], l[8];
#pragma unroll
  for (int j = 0; j < 8; ++j) {
    float v = W[(size_t)(k0 + j) * NOUT + col];
    h[j] = f2bf(v);
    l[j] = f2bf(v - bf2f(h[j]));
  }
  size_t fb = ((size_t)(nt * 4 + ks) * 64 + lane) * 8;
  size_t fragsz = (size_t)total * 8;
#pragma unroll
  for (int j = 0; j < 8; ++j) { pk[fb + j] = h[j]; pk[fragsz + fb + j] = l[j]; }
}

// ---------- Fused triple MFMA GEMM: all three outputs bf16 ----------
// unroll 2 on ks: compiler hoists iter k+1's W/A loads under iter k's MFMAs
// (W-frag latency was the stall at unroll 1; ~48 live W VGPRs is affordable).
__global__ __launch_bounds__(512)
void gemm3_mfma(const ushort* __restrict__ Ahi, const ushort* __restrict__ Alo,
                const ushort* __restrict__ W0, const ushort* __restrict__ W1,
                const ushort* __restrict__ W2,
                const float* __restrict__ b0, const float* __restrict__ b1,
                const float* __restrict__ b2,
                ushort* __restrict__ C0b, ushort* __restrict__ C1b,
                ushort* __restrict__ C2b, int M) {
  int tid = threadIdx.x;
  int w = tid >> 6, lane = tid & 63;
  int l15 = lane & 15, lh = lane >> 4;
  int row0 = blockIdx.x * 64;

  const ushort* Wp[3] = {W0, W1, W2};

  int arow[4];
#pragma unroll
  for (int mt = 0; mt < 4; ++mt) { int rr = row0 + mt * 16 + l15; arow[mt] = rr < M ? rr : M - 1; }

  float4v acc[3][4];
#pragma unroll
  for (int p = 0; p < 3; ++p)
#pragma unroll
    for (int mt = 0; mt < 4; ++mt) {
      acc[p][mt][0] = 0.f; acc[p][mt][1] = 0.f; acc[p][mt][2] = 0.f; acc[p][mt][3] = 0.f;
    }

  const size_t fragsz = (size_t)8 * 4 * 64 * 8;  // NT=8
#pragma unroll 2
  for (int ks = 0; ks < 4; ++ks) {
    short8v bh[3], bl[3];
    size_t fb = ((size_t)(w * 4 + ks) * 64 + lane) * 8;
#pragma unroll
    for (int p = 0; p < 3; ++p) {
      bh[p] = *(const short8v*)(Wp[p] + fb);
      bl[p] = *(const short8v*)(Wp[p] + fragsz + fb);
    }
#pragma unroll
    for (int mt = 0; mt < 4; ++mt) {
      size_t ao = (size_t)arow[mt] * 128 + ks * 32 + lh * 8;
      short8v ah = *(const short8v*)(Ahi + ao);
      short8v al = *(const short8v*)(Alo + ao);
#pragma unroll
      for (int p = 0; p < 3; ++p) {
        acc[p][mt] = __builtin_amdgcn_mfma_f32_16x16x32_bf16(ah, bh[p], acc[p][mt], 0, 0, 0);
        acc[p][mt] = __builtin_amdgcn_mfma_f32_16x16x32_bf16(ah, bl[p], acc[p][mt], 0, 0, 0);
        acc[p][mt] = __builtin_amdgcn_mfma_f32_16x16x32_bf16(al, bh[p], acc[p][mt], 0, 0, 0);
      }
    }
  }

  int col = w * 16 + l15;
  float bb0 = b0[col], bb1 = b1[col], bb2 = b2[col];
#pragma unroll
  for (int mt = 0; mt < 4; ++mt) {
#pragma unroll
    for (int r = 0; r < 4; ++r) {
      int rr = row0 + mt * 16 + lh * 4 + r;
      if (rr < M) {
        C0b[(size_t)rr * 128 + col] = f2bf(acc[0][mt][r] + bb0);
        C1b[(size_t)rr * 128 + col] = f2bf(acc[1][mt][r] + bb1);
        C2b[(size_t)rr * 128 + col] = f2bf(acc[2][mt][r] + bb2);
      }
    }
  }
}

// ---------- Fused MLP head: out = relu(A@W1+b1) @ W2 + b2 ----------
__global__ __launch_bounds__(256)
void mlp_fused(const ushort* __restrict__ Ahi, const ushort* __restrict__ Alo,
               const ushort* __restrict__ W1pk, const float* __restrict__ b1,
               const ushort* __restrict__ W2pk, const float* __restrict__ b2,
               float* __restrict__ out, int M) {
  __shared__ ushort m1[2][16][64][8];   // [hi/lo][k>>3][row][k&7]
  int tid = threadIdx.x;
  int w = tid >> 6, lane = tid & 63;
  int l15 = lane & 15, lh = lane >> 4;
  int row0 = blockIdx.x * 64;

  int arow[4];
#pragma unroll
  for (int mt = 0; mt < 4; ++mt) { int rr = row0 + mt * 16 + l15; arow[mt] = rr < M ? rr : M - 1; }

  float4v acc1[4][2];
#pragma unroll
  for (int mt = 0; mt < 4; ++mt)
#pragma unroll
    for (int j = 0; j < 2; ++j) {
      acc1[mt][j][0] = 0.f; acc1[mt][j][1] = 0.f; acc1[mt][j][2] = 0.f; acc1[mt][j][3] = 0.f;
    }
  const size_t fragsz1 = (size_t)8 * 4 * 64 * 8;
#pragma unroll 2
  for (int ks = 0; ks < 4; ++ks) {
    short8v bh[2], bl[2];
#pragma unroll
    for (int nt2 = 0; nt2 < 2; ++nt2) {
      size_t fb = ((size_t)((w * 2 + nt2) * 4 + ks) * 64 + lane) * 8;
      bh[nt2] = *(const short8v*)(W1pk + fb);
      bl[nt2] = *(const short8v*)(W1pk + fragsz1 + fb);
    }
#pragma unroll
    for (int mt = 0; mt < 4; ++mt) {
      size_t ao = (size_t)arow[mt] * 128 + ks * 32 + lh * 8;
      short8v ah = *(const short8v*)(Ahi + ao);
      short8v al = *(const short8v*)(Alo + ao);
#pragma unroll
      for (int nt2 = 0; nt2 < 2; ++nt2) {
        acc1[mt][nt2] = __builtin_amdgcn_mfma_f32_16x16x32_bf16(ah, bh[nt2], acc1[mt][nt2], 0, 0, 0);
        acc1[mt][nt2] = __builtin_amdgcn_mfma_f32_16x16x32_bf16(ah, bl[nt2], acc1[mt][nt2], 0, 0, 0);
        acc1[mt][nt2] = __builtin_amdgcn_mfma_f32_16x16x32_bf16(al, bh[nt2], acc1[mt][nt2], 0, 0, 0);
      }
    }
  }
#pragma unroll
  for (int nt2 = 0; nt2 < 2; ++nt2) {
    int col = (w * 2 + nt2) * 16 + l15;
    float bb = b1[col];
    int kf = col >> 3, kr = col & 7;
#pragma unroll
    for (int mt = 0; mt < 4; ++mt) {
#pragma unroll
      for (int r = 0; r < 4; ++r) {
        int row = mt * 16 + lh * 4 + r;
        float v = fmaxf(acc1[mt][nt2][r] + bb, 0.f);
        ushort h = f2bf(v);
        m1[0][kf][row][kr] = h;
        m1[1][kf][row][kr] = f2bf(v - bf2f(h));
      }
    }
  }
  __syncthreads();

  float4v acc2[4];
#pragma unroll
  for (int mt = 0; mt < 4; ++mt) {
    acc2[mt][0] = 0.f; acc2[mt][1] = 0.f; acc2[mt][2] = 0.f; acc2[mt][3] = 0.f;
  }
  const size_t fragsz2 = (size_t)4 * 4 * 64 * 8;
#pragma unroll 2
  for (int ks = 0; ks < 4; ++ks) {
    size_t fb = ((size_t)(w * 4 + ks) * 64 + lane) * 8;
    short8v bh = *(const short8v*)(W2pk + fb);
    short8v bl = *(const short8v*)(W2pk + fragsz2 + fb);
#pragma unroll
    for (int mt = 0; mt < 4; ++mt) {
      int row = mt * 16 + l15;
      short8v ah = *(const short8v*)&m1[0][ks * 4 + lh][row][0];
      short8v al = *(const short8v*)&m1[1][ks * 4 + lh][row][0];
      acc2[mt] = __builtin_amdgcn_mfma_f32_16x16x32_bf16(ah, bh, acc2[mt], 0, 0, 0);
      acc2[mt] = __builtin_amdgcn_mfma_f32_16x16x32_bf16(ah, bl, acc2[mt], 0, 0, 0);
      acc2[mt] = __builtin_amdgcn_mfma_f32_16x16x32_bf16(al, bh, acc2[mt], 0, 0, 0);
    }
  }
  int col = w * 16 + l15;
  float bb = b2[col];
#pragma unroll
  for (int mt = 0; mt < 4; ++mt) {
#pragma unroll
    for (int r = 0; r < 4; ++r) {
      int rr = row0 + mt * 16 + lh * 4 + r;
      if (rr < M) out[(size_t)rr * 64 + col] = acc2[mt][r] + bb;
    }
  }
}

// ---------- GATv2 aggregation: one wave per node, 2 edges per wave ----------
// xl, xr, skip all bf16. Self-loop is a regular CSR entry. leaky = mul+fma(|t|).
template<int H, bool SPLIT>
__global__ __launch_bounds__(256)
void gat_agg(const ushort* __restrict__ xlb, const ushort* __restrict__ xrb,
             const ushort* __restrict__ skb, const float* __restrict__ att,
             const float* __restrict__ gbias, const int* __restrict__ rowptr,
             const int* __restrict__ csr_src, float* __restrict__ out,
             ushort* __restrict__ outhi, ushort* __restrict__ outlo,
             int n, int relu) {
  constexpr int GL = (128 / H) / 4;  // lanes per head group: H=4 -> 8, H=1 -> 32
  int wid = blockIdx.x * (blockDim.x >> 6) + (threadIdx.x >> 6);
  if (wid >= n) return;
  int lane = threadIdx.x & 63;
  int half = lane >> 5;
  int sub = lane & 31;
  size_t base = (size_t)wid * 128 + sub * 4;
  uint2 ur = *(const uint2*)(xrb + base);
  float4 xrv;
  xrv.x = ubf(ur.x, 0); xrv.y = ubf(ur.x, 1);
  xrv.z = ubf(ur.y, 0); xrv.w = ubf(ur.y, 1);
  float4 av = *(const float4*)(att + sub * 4);
  float ax = 0.f, ay = 0.f, az = 0.f, aw = 0.f;
  float denom = 0.f;
  int e0 = rowptr[wid], e1 = rowptr[wid + 1];

  int idx = e0 + half;
  for (; idx + 2 < e1; idx += 4) {
    int s0 = csr_src[idx], s1 = csr_src[idx + 2];
    uint2 u0 = *(const uint2*)(xlb + (size_t)s0 * 128 + sub * 4);
    uint2 u1 = *(const uint2*)(xlb + (size_t)s1 * 128 + sub * 4);
    float4 v0, v1;
    v0.x = ubf(u0.x, 0); v0.y = ubf(u0.x, 1); v0.z = ubf(u0.y, 0); v0.w = ubf(u0.y, 1);
    v1.x = ubf(u1.x, 0); v1.y = ubf(u1.x, 1); v1.z = ubf(u1.y, 0); v1.w = ubf(u1.y, 1);
    float p0, p1;
    p0 = lrelu(v0.x + xrv.x) * av.x;
    p0 += lrelu(v0.y + xrv.y) * av.y;
    p0 += lrelu(v0.z + xrv.z) * av.z;
    p0 += lrelu(v0.w + xrv.w) * av.w;
    p1 = lrelu(v1.x + xrv.x) * av.x;
    p1 += lrelu(v1.y + xrv.y) * av.y;
    p1 += lrelu(v1.z + xrv.z) * av.z;
    p1 += lrelu(v1.w + xrv.w) * av.w;
#pragma unroll
    for (int o = 1; o < GL; o <<= 1) {
      p0 += __shfl_xor(p0, o, 64);
      p1 += __shfl_xor(p1, o, 64);
    }
    float w0 = __expf(p0), w1 = __expf(p1);
    denom += w0 + w1;
    ax += w0 * v0.x + w1 * v1.x;
    ay += w0 * v0.y + w1 * v1.y;
    az += w0 * v0.z + w1 * v1.z;
    aw += w0 * v0.w + w1 * v1.w;
  }
  for (; idx < e1; idx += 2) {
    int s0 = csr_src[idx];
    uint2 u0 = *(const uint2*)(xlb + (size_t)s0 * 128 + sub * 4);
    float4 v0;
    v0.x = ubf(u0.x, 0); v0.y = ubf(u0.x, 1); v0.z = ubf(u0.y, 0); v0.w = ubf(u0.y, 1);
    float p0;
    p0 = lrelu(v0.x + xrv.x) * av.x;
    p0 += lrelu(v0.y + xrv.y) * av.y;
    p0 += lrelu(v0.z + xrv.z) * av.z;
    p0 += lrelu(v0.w + xrv.w) * av.w;
#pragma unroll
    for (int o = 1; o < GL; o <<= 1) p0 += __shfl_xor(p0, o, 64);
    float w0 = __expf(p0);
    denom += w0;
    ax += w0 * v0.x;
    ay += w0 * v0.y;
    az += w0 * v0.z;
    aw += w0 * v0.w;
  }

  // combine the two halves
  ax += __shfl_xor(ax, 32, 64);
  ay += __shfl_xor(ay, 32, 64);
  az += __shfl_xor(az, 32, 64);
  aw += __shfl_xor(aw, 32, 64);
  denom += __shfl_xor(denom, 32, 64);

  if (half == 0) {
    float inv = 1.f / denom;
    uint2 us = *(const uint2*)(skb + base);
    float4 sk;
    sk.x = ubf(us.x, 0); sk.y = ubf(us.x, 1);
    sk.z = ubf(us.y, 0); sk.w = ubf(us.y, 1);
    float4 gb = *(const float4*)(gbias + sub * 4);
    float o0 = ax * inv + gb.x + sk.x;
    float o1 = ay * inv + gb.y + sk.y;
    float o2 = az * inv + gb.z + sk.z;
    float o3 = aw * inv + gb.w + sk.w;
    if (relu) {
      o0 = fmaxf(o0, 0.f); o1 = fmaxf(o1, 0.f);
      o2 = fmaxf(o2, 0.f); o3 = fmaxf(o3, 0.f);
    }
    if (SPLIT) {
      ushort h0 = f2bf(o0), h1 = f2bf(o1), h2 = f2bf(o2), h3 = f2bf(o3);
      *(ushort4*)(outhi + base) = make_ushort4(h0, h1, h2, h3);
      *(ushort4*)(outlo + base) = make_ushort4(f2bf(o0 - bf2f(h0)), f2bf(o1 - bf2f(h1)),
                                               f2bf(o2 - bf2f(h2)), f2bf(o3 - bf2f(h3)));
    } else {
      *(float4*)(out + base) = make_float4(o0, o1, o2, o3);
    }
  }
}

extern "C" void kernel_launch(void* const* d_in, const int* in_sizes, int n_in,
                              void* d_out, int out_size, void* d_ws, size_t ws_size,
                              hipStream_t stream) {
  const float* x       = (const float*)d_in[0];
  const int* ei        = (const int*)d_in[1];
  const float* Wl1     = (const float*)d_in[2];
  const float* bl1     = (const float*)d_in[3];
  const float* Wr1     = (const float*)d_in[4];
  const float* br1     = (const float*)d_in[5];
  const float* att1    = (const float*)d_in[6];
  const float* b1      = (const float*)d_in[7];
  const float* Wl2     = (const float*)d_in[8];
  const float* bl2     = (const float*)d_in[9];
  const float* Wr2     = (const float*)d_in[10];
  const float* br2     = (const float*)d_in[11];
  const float* att2    = (const float*)d_in[12];
  const float* b2      = (const float*)d_in[13];
  const float* skip1_w = (const float*)d_in[14];
  const float* skip1_b = (const float*)d_in[15];
  const float* skip2_w = (const float*)d_in[16];
  const float* skip2_b = (const float*)d_in[17];
  const float* mlp1_w  = (const float*)d_in[18];
  const float* mlp1_b  = (const float*)d_in[19];
  const float* mlp2_w  = (const float*)d_in[20];
  const float* mlp2_b  = (const float*)d_in[21];

  const int N = in_sizes[0] / 128;
  const int E = in_sizes[1] / 2;
  float* out = (float*)d_out;

  char* ws = (char*)d_ws;
  size_t off = 0;
  auto alloc = [&](size_t bytes) -> void* {
    void* p = ws + off;
    off = (off + bytes + 255) & ~(size_t)255;
    return p;
  };
  int* rowptr  = (int*)alloc((size_t)(N + 1) * sizeof(int));
  int* cnt     = (int*)alloc((size_t)N * sizeof(int));
  int* tscan   = (int*)alloc((size_t)N * sizeof(int));
  int* bsum    = (int*)alloc((size_t)1024 * sizeof(int));
  int* csr_src = (int*)alloc((size_t)(E + N) * sizeof(int));
  ushort* wpk[8];
  for (int i = 0; i < 8; ++i) wpk[i] = (ushort*)alloc(128 * 128 * 2 * sizeof(ushort));
  ushort* p0hi = (ushort*)alloc((size_t)N * 128 * sizeof(ushort));
  ushort* p0lo = (ushort*)alloc((size_t)N * 128 * sizeof(ushort));
  ushort* xlb  = (ushort*)alloc((size_t)N * 128 * sizeof(ushort));
  ushort* xrb  = (ushort*)alloc((size_t)N * 128 * sizeof(ushort));
  ushort* skb  = (ushort*)alloc((size_t)N * 128 * sizeof(ushort));

  const int* srcp = ei;
  const int* dstp = ei + E;

  const int ggrid = (N + 63) / 64;
  const int agrid = (N + 3) / 4;
  const int nb = (N + 1023) / 1024;
  const int PARTB = 2048;

  // CSR by dst with embedded self-loops (partitioned count/fill)
  hipMemsetAsync(cnt, 0, (size_t)N * sizeof(int), stream);
  count_part<<<PARTB, 256, 0, stream>>>(dstp, cnt, E, N, PARTB);
  scan_blocks<<<nb, 1024, 0, stream>>>(cnt, tscan, bsum, N);
  scan_final<<<nb, 1024, 0, stream>>>(cnt, tscan, bsum, rowptr, csr_src, N, nb);
  fill_part<<<PARTB, 256, 0, stream>>>(srcp, dstp, rowptr, cnt, csr_src, E, N, PARTB);

  // Weight packs (one launch) + x split
  PackArgs pa;
  pa.w[0] = Wl1;    pa.o[0] = wpk[0]; pa.nout[0] = 128;
  pa.w[1] = Wr1;    pa.o[1] = wpk[1]; pa.nout[1] = 128;
  pa.w[2] = skip1_w;pa.o[2] = wpk[2]; pa.nout[2] = 128;
  pa.w[3] = Wl2;    pa.o[3] = wpk[3]; pa.nout[3] = 128;
  pa.w[4] = Wr2;    pa.o[4] = wpk[4]; pa.nout[4] = 128;
  pa.w[5] = skip2_w;pa.o[5] = wpk[5]; pa.nout[5] = 128;
  pa.w[6] = mlp1_w; pa.o[6] = wpk[6]; pa.nout[6] = 128;
  pa.w[7] = mlp2_w; pa.o[7] = wpk[7]; pa.nout[7] = 64;
  pack_all<<<64, 256, 0, stream>>>(pa);
  split_f32<<<(N * 128 / 4 + 255) / 256, 256, 0, stream>>>(x, p0hi, p0lo, N * 128);

  // ---- Layer 1: fused {xl1, xr1, skip1} GEMM, then agg ----
  gemm3_mfma<<<ggrid, 512, 0, stream>>>(p0hi, p0lo, wpk[0], wpk[1], wpk[2],
                                        bl1, br1, skip1_b, xlb, xrb, skb, N);
  gat_agg<4, true><<<agrid, 256, 0, stream>>>(xlb, xrb, skb, att1, b1,
                                              rowptr, csr_src, nullptr, p0hi, p0lo, N, 1);

  // ---- Layer 2: fused {xl2, xr2, skip2} GEMM, then agg ----
  gemm3_mfma<<<ggrid, 512, 0, stream>>>(p0hi, p0lo, wpk[3], wpk[4], wpk[5],
                                        bl2, br2, skip2_b, xlb, xrb, skb, N);
  gat_agg<1, true><<<agrid, 256, 0, stream>>>(xlb, xrb, skb, att2, b2,
                                              rowptr, csr_src, nullptr, p0hi, p0lo, N, 0);

  // ---- Fused MLP head ----
  mlp_fused<<<ggrid, 256, 0, stream>>>(p0hi, p0lo, wpk[6], mlp1_b, wpk[7], mlp2_b, out, N);
}